// Round 1
// 320.157 us; speedup vs baseline: 1.1336x; 1.1336x over previous
//
#include <hip/hip_runtime.h>

// SoftDecisionTree fused pipeline for MI355X (gfx950).
// Inputs: x[16384,2048] f32, y[16384,1000] f32 one-hot, W[255,2048] f32,
//         b[255] f32, beta[255] f32, leaf_params[256,1000] f32
// Output: [loss(1) | output(16384*1000)] f32
//
// Pipeline:
//  1. prep_w:       W -> bf16 FRAGMENT-MAJOR WbP[kt][tile16][lane][8]; pad b/beta
//  2. leaf_softmax: logQT[class][leaf] = log_softmax(leaf_params)^T, Q = exp(logQ)
//  3. find_targets: t_i = argmax_j y[i,j]
//  4. gemm_tree:    fused x@W^T (bf16 MFMA, A via swizzled global_load_lds,
//                   B direct-to-reg from L2) + sigmoid + tree walk + node sums +
//                   logQT dot + argmax. No P round-trip to HBM.
//  5. finalize_loss
//  6. gather_rows:  d_out[1+i*1000 ..] = Q[best_i]

typedef __attribute__((ext_vector_type(8))) short short8;
typedef __attribute__((ext_vector_type(4))) float f32x4;

#define DIM 2048
#define NCLS 1000
#define NINNER 255
#define NPAD 256
#define BM 32        // rows per block
#define CHUNKF 128   // k-floats per staged chunk (4 MFMA k-steps)
#define NCHUNK 16    // 2048 / 128

__device__ __forceinline__ unsigned cvt2bf(float a, float b) {
  // round-half-up fp32 -> bf16, packed pair (identical to verified baseline)
  return ((__float_as_uint(a) + 0x8000u) >> 16) | ((__float_as_uint(b) + 0x8000u) & 0xFFFF0000u);
}

__device__ __forceinline__ void async_copy16(const float* gsrc, void* ldst) {
  __builtin_amdgcn_global_load_lds(
      (const __attribute__((address_space(1))) unsigned int*)(gsrc),
      (__attribute__((address_space(3))) unsigned int*)(ldst), 16, 0, 0);
}

// W -> fragment-major bf16: WbP[((kt*16 + T)*64 + lane)*8 + e] =
//   bf16(W[T*16 + (lane&15)][kt*32 + (lane>>4)*8 + e]);  row 255 zero pad.
// Each wave's B-fragment load in the GEMM becomes one coalesced 16B/lane read.
__global__ __launch_bounds__(256) void prep_w(const float* __restrict__ W,
                                              const float* __restrict__ b,
                                              const float* __restrict__ beta,
                                              unsigned short* __restrict__ WbP,
                                              float* __restrict__ bp,
                                              float* __restrict__ betap) {
  int f = blockIdx.x * 256 + threadIdx.x;  // 0..65535 fragments
  int kt = f >> 10;
  int T = (f >> 6) & 15;
  int l = f & 63;
  int row = T * 16 + (l & 15);
  int k0 = kt * 32 + (l >> 4) * 8;
  uint4 o = make_uint4(0u, 0u, 0u, 0u);
  if (row < NINNER) {
    const float* src = W + (size_t)row * DIM + k0;
    o.x = cvt2bf(src[0], src[1]);
    o.y = cvt2bf(src[2], src[3]);
    o.z = cvt2bf(src[4], src[5]);
    o.w = cvt2bf(src[6], src[7]);
  }
  *(uint4*)(WbP + (size_t)f * 8) = o;
  if (f < NPAD) {
    bp[f] = (f < NINNER) ? b[f] : 0.f;
    betap[f] = (f < NINNER) ? beta[f] : 0.f;
  }
}

__global__ __launch_bounds__(256) void leaf_softmax(const float* __restrict__ leaf,
                                                    float* __restrict__ logQT,
                                                    float* __restrict__ Q) {
  int l = blockIdx.x, t = threadIdx.x;
  const float* row = leaf + (size_t)l * NCLS;
  __shared__ float red[256];
  float mx = -3.4e38f;
  for (int j = t; j < NCLS; j += 256) mx = fmaxf(mx, row[j]);
  red[t] = mx; __syncthreads();
  for (int s = 128; s; s >>= 1) { if (t < s) red[t] = fmaxf(red[t], red[t + s]); __syncthreads(); }
  mx = red[0]; __syncthreads();
  float sm = 0.f;
  for (int j = t; j < NCLS; j += 256) sm += __expf(row[j] - mx);
  red[t] = sm; __syncthreads();
  for (int s = 128; s; s >>= 1) { if (t < s) red[t] += red[t + s]; __syncthreads(); }
  float lse = mx + __logf(red[0]);
  for (int j = t; j < NCLS; j += 256) {
    float lg = row[j] - lse;
    logQT[(size_t)j * NPAD + l] = lg;      // transposed: [class][leaf]
    Q[(size_t)l * NCLS + j] = __expf(lg);
  }
}

__global__ __launch_bounds__(256) void find_targets(const float* __restrict__ y,
                                                    int* __restrict__ tgt) {
  int wv = threadIdx.x >> 6, lane = threadIdx.x & 63;
  int r = blockIdx.x * 4 + wv;
  const float4* yr = (const float4*)(y + (size_t)r * NCLS);
  int found = 0x7fffffff;
#pragma unroll
  for (int i = 0; i < 4; ++i) {
    int j4 = i * 64 + lane;
    if (j4 < 250) {
      float4 v = yr[j4];
      if (v.x > 0.5f) found = min(found, 4 * j4 + 0);
      if (v.y > 0.5f) found = min(found, 4 * j4 + 1);
      if (v.z > 0.5f) found = min(found, 4 * j4 + 2);
      if (v.w > 0.5f) found = min(found, 4 * j4 + 3);
    }
  }
  for (int off = 32; off; off >>= 1) found = min(found, __shfl_down(found, off));
  if (lane == 0) tgt[r] = found;
}

// One chunk = 4 MFMA k-steps (k += 128). A read from swizzled LDS (f32 -> bf16
// pack at read), B frags straight from L2-resident WbP. 8 MFMA / k-step / wave.
__device__ __forceinline__ void chunk_mma(f32x4 (&ac)[2][4], const float* Ab,
                                          const unsigned short* bptr, int c,
                                          int frow, int fq) {
#pragma unroll
  for (int s = 0; s < 4; ++s) {
    int kt = c * 4 + s;
    short8 bfr[4];
#pragma unroll
    for (int nt = 0; nt < 4; ++nt)
      bfr[nt] = *(const short8*)(bptr + ((size_t)kt * 1024 + nt * 64) * 8);
    short8 afr[2];
#pragma unroll
    for (int mt = 0; mt < 2; ++mt) {
      int R = mt * 16 + frow;
      int r7 = R & 7;
      const float4* base = (const float4*)(Ab + R * 128 + s * 32);
      float4 va = base[(2 * fq) ^ r7];        // XOR-swizzled 16B slots
      float4 vb = base[(2 * fq + 1) ^ r7];
      union { uint4 u; short8 s8; } cv;
      cv.u.x = cvt2bf(va.x, va.y);
      cv.u.y = cvt2bf(va.z, va.w);
      cv.u.z = cvt2bf(vb.x, vb.y);
      cv.u.w = cvt2bf(vb.z, vb.w);
      afr[mt] = cv.s8;
    }
#pragma unroll
    for (int nt = 0; nt < 4; ++nt)
#pragma unroll
      for (int mt = 0; mt < 2; ++mt)
        ac[mt][nt] = __builtin_amdgcn_mfma_f32_16x16x32_bf16(afr[mt], bfr[nt], ac[mt][nt], 0, 0, 0);
  }
}

// Fused GEMM + sigmoid + tree walk. 512 blocks x 256 threads (4 waves), 2 blocks/CU.
// Wave tile 32x64 (wave n-quadrant), block tile 32x256 (full node width).
// Two accumulator halves (k<1024 / k>=1024) reproduce the previous kernel's
// P0+P1 summation order bit-exactly.
__global__ __launch_bounds__(256, 2) void gemm_tree(
    const float* __restrict__ x, const unsigned short* __restrict__ WbP,
    const float* __restrict__ bp, const float* __restrict__ betap,
    const float* __restrict__ logQT, const int* __restrict__ tgt,
    float* __restrict__ acc, int* __restrict__ best) {
  __shared__ __align__(16) float As[2][4096];  // 2 x 16 KB A chunk buffers; reused as P[32][256]
  __shared__ float s0s[127], s1s[127], sdot;

  int tid = threadIdx.x;
  int lane = tid & 63, wave = tid >> 6;
  int frow = lane & 15, fq = lane >> 4;
  int m_base = blockIdx.x * BM;

  if (tid < 127) { s0s[tid] = 0.f; s1s[tid] = 0.f; }
  if (tid == 255) sdot = 0.f;

  // A staging map: linear LDS byte L = a*4096 + tid*16 holds global 16B chunk
  // (row r = L>>9, slot j=(L>>4)&31 -> logical c16 = (j&24)|((j&7)^(r&7))).
  // Involution: read of logical c16 uses slot (c16&24)|((c16&7)^(r&7)).
  const float* asrc[4];
  int aoff[4];
#pragma unroll
  for (int a = 0; a < 4; ++a) {
    int L = a * 4096 + tid * 16;
    int r = L >> 9;            // a*8 + (tid>>5)
    int j = (L >> 4) & 31;     // tid & 31
    int c16 = (j & 24) | ((j & 7) ^ (r & 7));
    asrc[a] = x + (size_t)(m_base + r) * DIM + c16 * 4;
    aoff[a] = L;
  }

  const unsigned short* bptr = WbP + ((size_t)wave * 256 + lane) * 8;

  f32x4 accA[2][4] = {}, accB[2][4] = {};

  // prologue: stage chunk 0
#pragma unroll
  for (int a = 0; a < 4; ++a) async_copy16(asrc[a], (char*)As[0] + aoff[a]);
  __syncthreads();  // implicit vmcnt(0): chunk 0 landed

  for (int c = 0; c < NCHUNK; ++c) {
    if (c + 1 < NCHUNK) {  // issue next-chunk prefetch BEFORE compute (T3 2-phase)
      float* nb = As[(c + 1) & 1];
#pragma unroll
      for (int a = 0; a < 4; ++a)
        async_copy16(asrc[a] + (c + 1) * CHUNKF, (char*)nb + aoff[a]);
    }
    const float* Ab = As[c & 1];
    if (c < 8) chunk_mma(accA, Ab, bptr, c, frow, fq);
    else       chunk_mma(accB, Ab, bptr, c, frow, fq);
    __syncthreads();  // drains vmcnt(0): next chunk visible + buffer reads done
  }

  // ---- fused epilogue: accumulators -> LDS P tile (reuses both A buffers) ----
  float* Ps = &As[0][0];  // 32 rows x 256 cols f32 = 32 KB
#pragma unroll
  for (int mt = 0; mt < 2; ++mt)
#pragma unroll
    for (int nt = 0; nt < 4; ++nt)
#pragma unroll
      for (int rg = 0; rg < 4; ++rg)
        Ps[(mt * 16 + fq * 4 + rg) * 256 + wave * 64 + nt * 16 + frow] =
            accA[mt][nt][rg] + accB[mt][nt][rg];  // == (P0 + P1), same order as before
  __syncthreads();

  // sigmoid in place: thread owns column tid across all 32 rows
  {
    float bc = bp[tid], bec = betap[tid];
#pragma unroll 4
    for (int i = 0; i < 32; ++i) {
      float v = Ps[i * 256 + tid];
      Ps[i * 256 + tid] = 1.f / (1.f + __expf(-bec * (v + bc)));
    }
  }
  __syncthreads();

  // tree walk: wave handles rows wave*8 .. +8; node sums accumulated in regs
  float wdot = 0.f;
  float s0r[7] = {}, s1r[7] = {};
  for (int it = 0; it < 8; ++it) {
    int rl = wave * 8 + it;
    int r = m_base + rl;
    const float* wsp = Ps + rl * 256;
    int tg = tgt[r];
    float pp = 1.f;  // path product into current depth
#pragma unroll
    for (int d = 1; d <= 6; ++d) {
      int idx = (1 << (d - 1)) - 1 + (lane >> (7 - d));
      float p = wsp[idx];
      s0r[d - 1] += pp;       // only first covering lane's value is used later
      s1r[d - 1] += p * pp;
      pp *= ((lane >> (6 - d)) & 1) ? p : (1.f - p);
    }
    float p7 = wsp[63 + lane];
    s0r[6] += pp;
    s1r[6] += p7 * pp;
    float pL = pp * (1.f - p7), pR = pp * p7;
    float p8a = wsp[127 + 2 * lane], p8b = wsp[128 + 2 * lane];
    float lf0 = pL * (1.f - p8a), lf1 = pL * p8a;
    float lf2 = pR * (1.f - p8b), lf3 = pR * p8b;
    float4 lq = *(const float4*)(logQT + (size_t)tg * NPAD + lane * 4);
    wdot += lf0 * lq.x + lf1 * lq.y + lf2 * lq.z + lf3 * lq.w;
    float bv = lf0; int bi = 4 * lane;
    if (lf1 > bv) { bv = lf1; bi = 4 * lane + 1; }
    if (lf2 > bv) { bv = lf2; bi = 4 * lane + 2; }
    if (lf3 > bv) { bv = lf3; bi = 4 * lane + 3; }
    for (int off = 32; off; off >>= 1) {
      float ov = __shfl_down(bv, off);
      int oi = __shfl_down(bi, off);
      if (ov > bv || (ov == bv && oi < bi)) { bv = ov; bi = oi; }  // first-max tie-break
    }
    if (lane == 0) best[r] = bi;
  }
  // fold per-wave node sums into block LDS arrays
#pragma unroll
  for (int d = 1; d <= 6; ++d) {
    int idx = (1 << (d - 1)) - 1 + (lane >> (7 - d));
    if ((lane & ((1 << (7 - d)) - 1)) == 0) {
      atomicAdd(&s0s[idx], s0r[d - 1]);
      atomicAdd(&s1s[idx], s1r[d - 1]);
    }
  }
  atomicAdd(&s0s[63 + lane], s0r[6]);
  atomicAdd(&s1s[63 + lane], s1r[6]);
  for (int off = 32; off; off >>= 1) wdot += __shfl_down(wdot, off);
  if (lane == 0) atomicAdd(&sdot, wdot);
  __syncthreads();
  if (tid < 127) {
    atomicAdd(&acc[tid], s0s[tid]);
    atomicAdd(&acc[127 + tid], s1s[tid]);
  }
  if (tid == 255) atomicAdd(&acc[254], sdot);
}

__global__ __launch_bounds__(128) void finalize_loss(const float* __restrict__ acc,
                                                     float* __restrict__ out) {
  __shared__ float red[128];
  int t = threadIdx.x;
  float c = 0.f;
  if (t < 127) {
    float denom = acc[t];
    if (denom == 0.f) denom = 1e-6f;
    float alpha = acc[127 + t] / denom;
    alpha = fminf(fmaxf(alpha, 1e-6f), 1.f - 1e-6f);
    int d = 31 - __clz(t + 1) + 1;  // depth: idx 0 -> 1, idx 1..2 -> 2, ...
    float lm = 0.1f * exp2f(-(float)d);
    c = -lm * 0.5f * (logf(alpha) + log1pf(-alpha));
  }
  red[t] = c;
  __syncthreads();
  for (int s = 64; s; s >>= 1) { if (t < s) red[t] += red[t + s]; __syncthreads(); }
  if (t == 0) out[0] = -(acc[254] / 16384.f) + red[0];
}

__global__ __launch_bounds__(256) void gather_rows(const float* __restrict__ Q,
                                                   const int* __restrict__ best,
                                                   float* __restrict__ out) {
  int wv = threadIdx.x >> 6, lane = threadIdx.x & 63;
  int r = blockIdx.x * 4 + wv;
  const float* src = Q + (size_t)best[r] * NCLS;
  float* dst = out + 1 + (size_t)r * NCLS;  // rows start at global index 1+1000r
  if (lane < 3) dst[lane] = src[lane];
  if (lane == 0) dst[999] = src[999];
#pragma unroll
  for (int i = 0; i < 4; ++i) {
    int q = i * 64 + lane;
    if (q < 249) {
      int o = 3 + 4 * q;  // 16B-aligned in dst
      float4 v = make_float4(src[o], src[o + 1], src[o + 2], src[o + 3]);
      *(float4*)(dst + o) = v;
    }
  }
}

extern "C" void kernel_launch(void* const* d_in, const int* in_sizes, int n_in,
                              void* d_out, int out_size, void* d_ws, size_t ws_size,
                              hipStream_t stream) {
  const float* x = (const float*)d_in[0];
  const float* y = (const float*)d_in[1];
  const float* W = (const float*)d_in[2];
  const float* b = (const float*)d_in[3];
  const float* beta = (const float*)d_in[4];
  const float* leaf = (const float*)d_in[5];
  float* out = (float*)d_out;
  char* ws = (char*)d_ws;

  unsigned short* WbP = (unsigned short*)(ws + 0);       // 1048576 (fragment-major)
  float* bp    = (float*)(ws + 1048576);                 // 1024
  float* betap = (float*)(ws + 1049600);                 // 1024
  float* accb  = (float*)(ws + 1050624);                 // 1024 (255 used)
  int* tgt     = (int*)(ws + 1051648);                   // 65536
  int* best    = (int*)(ws + 1117184);                   // 65536
  float* logQT = (float*)(ws + 1182720);                 // 1000*256*4 = 1024000
  float* Q     = (float*)(ws + 2206720);                 // 1024000

  prep_w<<<256, 256, 0, stream>>>(W, b, beta, WbP, bp, betap);
  leaf_softmax<<<256, 256, 0, stream>>>(leaf, logQT, Q);
  find_targets<<<4096, 256, 0, stream>>>(y, tgt);
  hipMemsetAsync(accb, 0, 256 * sizeof(float), stream);
  gemm_tree<<<512, 256, 0, stream>>>(x, WbP, bp, betap, logQT, tgt, accb, best);
  finalize_loss<<<1, 128, 0, stream>>>(accb, out);
  gather_rows<<<4096, 256, 0, stream>>>(Q, best, out);
}

// Round 2
// 311.746 us; speedup vs baseline: 1.1642x; 1.0270x over previous
//
#include <hip/hip_runtime.h>

// SoftDecisionTree fused pipeline for MI355X (gfx950).
// Inputs: x[16384,2048] f32, y[16384,1000] f32 one-hot, W[255,2048] f32,
//         b[255] f32, beta[255] f32, leaf_params[256,1000] f32
// Output: [loss(1) | output(16384*1000)] f32
//
// gemm_tree v2: counted-vmcnt software pipeline (T3+T4).
//  - B-fragment loads issued BEFORE the A-prefetch each chunk, so the
//    compiler's B-use waits are vmcnt(>=4) and never drain the prefetch
//    (vmcnt retires in FIFO issue order -- round-1's serialization bug).
//  - 3 LDS chunk buffers, prefetch depth 2, raw s_barrier (no vmcnt(0) drain).
//  - Accumulation order bit-identical to the verified round-1 kernel.

typedef __attribute__((ext_vector_type(8))) short short8;
typedef __attribute__((ext_vector_type(4))) float f32x4;

#define DIM 2048
#define NCLS 1000
#define NINNER 255
#define NPAD 256
#define BM 32        // rows per block
#define CHUNKF 128   // k-floats per staged chunk (4 MFMA k-steps)
#define NCHUNK 16    // 2048 / 128

__device__ __forceinline__ unsigned cvt2bf(float a, float b) {
  // round-half-up fp32 -> bf16, packed pair (identical to verified baseline)
  return ((__float_as_uint(a) + 0x8000u) >> 16) | ((__float_as_uint(b) + 0x8000u) & 0xFFFF0000u);
}

__device__ __forceinline__ void async_copy16(const float* gsrc, void* ldst) {
  __builtin_amdgcn_global_load_lds(
      (const __attribute__((address_space(1))) unsigned int*)(gsrc),
      (__attribute__((address_space(3))) unsigned int*)(ldst), 16, 0, 0);
}

// W -> fragment-major bf16: WbP[((kt*16 + T)*64 + lane)*8 + e] =
//   bf16(W[T*16 + (lane&15)][kt*32 + (lane>>4)*8 + e]);  row 255 zero pad.
__global__ __launch_bounds__(256) void prep_w(const float* __restrict__ W,
                                              const float* __restrict__ b,
                                              const float* __restrict__ beta,
                                              unsigned short* __restrict__ WbP,
                                              float* __restrict__ bp,
                                              float* __restrict__ betap) {
  int f = blockIdx.x * 256 + threadIdx.x;  // 0..65535 fragments
  int kt = f >> 10;
  int T = (f >> 6) & 15;
  int l = f & 63;
  int row = T * 16 + (l & 15);
  int k0 = kt * 32 + (l >> 4) * 8;
  uint4 o = make_uint4(0u, 0u, 0u, 0u);
  if (row < NINNER) {
    const float* src = W + (size_t)row * DIM + k0;
    o.x = cvt2bf(src[0], src[1]);
    o.y = cvt2bf(src[2], src[3]);
    o.z = cvt2bf(src[4], src[5]);
    o.w = cvt2bf(src[6], src[7]);
  }
  *(uint4*)(WbP + (size_t)f * 8) = o;
  if (f < NPAD) {
    bp[f] = (f < NINNER) ? b[f] : 0.f;
    betap[f] = (f < NINNER) ? beta[f] : 0.f;
  }
}

__global__ __launch_bounds__(256) void leaf_softmax(const float* __restrict__ leaf,
                                                    float* __restrict__ logQT,
                                                    float* __restrict__ Q) {
  int l = blockIdx.x, t = threadIdx.x;
  const float* row = leaf + (size_t)l * NCLS;
  __shared__ float red[256];
  float mx = -3.4e38f;
  for (int j = t; j < NCLS; j += 256) mx = fmaxf(mx, row[j]);
  red[t] = mx; __syncthreads();
  for (int s = 128; s; s >>= 1) { if (t < s) red[t] = fmaxf(red[t], red[t + s]); __syncthreads(); }
  mx = red[0]; __syncthreads();
  float sm = 0.f;
  for (int j = t; j < NCLS; j += 256) sm += __expf(row[j] - mx);
  red[t] = sm; __syncthreads();
  for (int s = 128; s; s >>= 1) { if (t < s) red[t] += red[t + s]; __syncthreads(); }
  float lse = mx + __logf(red[0]);
  for (int j = t; j < NCLS; j += 256) {
    float lg = row[j] - lse;
    logQT[(size_t)j * NPAD + l] = lg;      // transposed: [class][leaf]
    Q[(size_t)l * NCLS + j] = __expf(lg);
  }
}

__global__ __launch_bounds__(256) void find_targets(const float* __restrict__ y,
                                                    int* __restrict__ tgt) {
  int wv = threadIdx.x >> 6, lane = threadIdx.x & 63;
  int r = blockIdx.x * 4 + wv;
  const float4* yr = (const float4*)(y + (size_t)r * NCLS);
  int found = 0x7fffffff;
#pragma unroll
  for (int i = 0; i < 4; ++i) {
    int j4 = i * 64 + lane;
    if (j4 < 250) {
      float4 v = yr[j4];
      if (v.x > 0.5f) found = min(found, 4 * j4 + 0);
      if (v.y > 0.5f) found = min(found, 4 * j4 + 1);
      if (v.z > 0.5f) found = min(found, 4 * j4 + 2);
      if (v.w > 0.5f) found = min(found, 4 * j4 + 3);
    }
  }
  for (int off = 32; off; off >>= 1) found = min(found, __shfl_down(found, off));
  if (lane == 0) tgt[r] = found;
}

// One pipelined chunk phase. Program order (crucial for vmcnt FIFO):
//   [16 B-frag loads] -> [4 A-prefetch global_load_lds] -> vmcnt(VW) ->
//   s_barrier -> compute -> sched_barrier -> s_barrier
// VW leaves the newer prefetches outstanding; B-use waits are vmcnt(>=4).
template <int VW, bool PF>
__device__ __forceinline__ void do_chunk(f32x4 (&ac)[2][4], const float* Ab,
                                         const unsigned short* bc,
                                         const float* const* ps, const int* aoff,
                                         float* nbuf, int frow, int fq) {
  short8 bfr[4][4];
#pragma unroll
  for (int s = 0; s < 4; ++s)
#pragma unroll
    for (int nt = 0; nt < 4; ++nt)
      bfr[s][nt] = *(const short8*)(bc + s * 8192 + nt * 512);
  asm volatile("" ::: "memory");  // pin: B loads issue before the prefetch below
  if (PF) {
#pragma unroll
    for (int a = 0; a < 4; ++a) async_copy16(ps[a], (char*)nbuf + aoff[a]);
  }
  asm volatile("s_waitcnt vmcnt(%0)" ::"n"(VW) : "memory");  // own chunk-c copies retired
  __builtin_amdgcn_s_barrier();                              // everyone's chunk-c visible
#pragma unroll
  for (int s = 0; s < 4; ++s) {
    short8 afr[2];
#pragma unroll
    for (int mt = 0; mt < 2; ++mt) {
      int R = mt * 16 + frow;
      int r7 = R & 7;
      const float4* base = (const float4*)(Ab + R * 128 + s * 32);
      float4 va = base[(2 * fq) ^ r7];  // XOR-swizzled 16B slots
      float4 vb = base[(2 * fq + 1) ^ r7];
      union { uint4 u; short8 s8; } cv;
      cv.u.x = cvt2bf(va.x, va.y);
      cv.u.y = cvt2bf(va.z, va.w);
      cv.u.z = cvt2bf(vb.x, vb.y);
      cv.u.w = cvt2bf(vb.z, vb.w);
      afr[mt] = cv.s8;
    }
#pragma unroll
    for (int nt = 0; nt < 4; ++nt)
#pragma unroll
      for (int mt = 0; mt < 2; ++mt)
        ac[mt][nt] = __builtin_amdgcn_mfma_f32_16x16x32_bf16(afr[mt], bfr[s][nt], ac[mt][nt], 0, 0, 0);
  }
  __builtin_amdgcn_sched_barrier(0);  // no use sinks past the buffer-release barrier
  __builtin_amdgcn_s_barrier();       // all waves done reading Ab -> buffer reusable
}

// Fused GEMM + sigmoid + tree walk. 512 blocks x 256 threads (4 waves), 2 blocks/CU.
// Wave tile 32x64 (wave n-quadrant). Two accumulator halves (k<1024 / k>=1024)
// reproduce the original P0+P1 summation order bit-exactly.
__global__ __launch_bounds__(256, 2) void gemm_tree(
    const float* __restrict__ x, const unsigned short* __restrict__ WbP,
    const float* __restrict__ bp, const float* __restrict__ betap,
    const float* __restrict__ logQT, const int* __restrict__ tgt,
    float* __restrict__ acc, int* __restrict__ best) {
  __shared__ __align__(16) float As[3][4096];  // 3 x 16 KB chunk buffers; [0..1] reused as P[32][256]
  __shared__ float s0s[127], s1s[127], sdot;

  int tid = threadIdx.x;
  int lane = tid & 63, wave = tid >> 6;
  int frow = lane & 15, fq = lane >> 4;
  int m_base = blockIdx.x * BM;

  if (tid < 127) { s0s[tid] = 0.f; s1s[tid] = 0.f; }
  if (tid == 255) sdot = 0.f;

  // A staging map: linear LDS byte L = a*4096 + tid*16 holds global 16B chunk
  // (row r = L>>9, slot j=(L>>4)&31 -> logical c16 = (j&24)|((j&7)^(r&7))).
  const float* asrc[4];
  int aoff[4];
#pragma unroll
  for (int a = 0; a < 4; ++a) {
    int L = a * 4096 + tid * 16;
    int r = L >> 9;            // a*8 + (tid>>5)
    int j = (L >> 4) & 31;     // tid & 31
    int c16 = (j & 24) | ((j & 7) ^ (r & 7));
    asrc[a] = x + (size_t)(m_base + r) * DIM + c16 * 4;
    aoff[a] = L;
  }

  const unsigned short* bptr = WbP + ((size_t)wave * 256 + lane) * 8;

  f32x4 accA[2][4] = {}, accB[2][4] = {};

  // prologue: stage chunks 0 and 1
#pragma unroll
  for (int a = 0; a < 4; ++a) async_copy16(asrc[a], (char*)As[0] + aoff[a]);
#pragma unroll
  for (int a = 0; a < 4; ++a) async_copy16(asrc[a] + CHUNKF, (char*)As[1] + aoff[a]);

  float *bA = As[0], *bB = As[1], *bC = As[2];
  const float* ps[4];
#pragma unroll
  for (int a = 0; a < 4; ++a) ps[a] = asrc[a] + 2 * CHUNKF;
  const unsigned short* bc = bptr;

  for (int c = 0; c < 8; ++c) {  // k < 1024 half
    do_chunk<24, true>(accA, bA, bc, ps, aoff, bC, frow, fq);
    float* t = bA; bA = bB; bB = bC; bC = t;
    bc += 32768;
#pragma unroll
    for (int a = 0; a < 4; ++a) ps[a] += CHUNKF;
  }
  for (int c = 0; c < 6; ++c) {  // k >= 1024 half, still prefetching
    do_chunk<24, true>(accB, bA, bc, ps, aoff, bC, frow, fq);
    float* t = bA; bA = bB; bB = bC; bC = t;
    bc += 32768;
#pragma unroll
    for (int a = 0; a < 4; ++a) ps[a] += CHUNKF;
  }
  // peeled tail: no more prefetches; wait counts shrink as FIFO drains
  do_chunk<20, false>(accB, bA, bc, ps, aoff, bC, frow, fq);
  { float* t = bA; bA = bB; bB = bC; bC = t; }
  bc += 32768;
  do_chunk<16, false>(accB, bA, bc, ps, aoff, bC, frow, fq);

  __syncthreads();  // full drain before reusing As[0..1] as the P tile

  // ---- fused epilogue: accumulators -> LDS P tile ----
  float* Ps = &As[0][0];  // 32 rows x 256 cols f32 = 32 KB (As[0]+As[1])
#pragma unroll
  for (int mt = 0; mt < 2; ++mt)
#pragma unroll
    for (int nt = 0; nt < 4; ++nt)
#pragma unroll
      for (int rg = 0; rg < 4; ++rg)
        Ps[(mt * 16 + fq * 4 + rg) * 256 + wave * 64 + nt * 16 + frow] =
            accA[mt][nt][rg] + accB[mt][nt][rg];  // == (P0 + P1), same order as before
  __syncthreads();

  // sigmoid in place: thread owns column tid across all 32 rows
  {
    float bc2 = bp[tid], bec = betap[tid];
#pragma unroll 4
    for (int i = 0; i < 32; ++i) {
      float v = Ps[i * 256 + tid];
      Ps[i * 256 + tid] = 1.f / (1.f + __expf(-bec * (v + bc2)));
    }
  }
  __syncthreads();

  // tree walk: wave handles rows wave*8 .. +8; node sums accumulated in regs
  float wdot = 0.f;
  float s0r[7] = {}, s1r[7] = {};
  for (int it = 0; it < 8; ++it) {
    int rl = wave * 8 + it;
    int r = m_base + rl;
    const float* wsp = Ps + rl * 256;
    int tg = tgt[r];
    float pp = 1.f;  // path product into current depth
#pragma unroll
    for (int d = 1; d <= 6; ++d) {
      int idx = (1 << (d - 1)) - 1 + (lane >> (7 - d));
      float p = wsp[idx];
      s0r[d - 1] += pp;       // only first covering lane's value is used later
      s1r[d - 1] += p * pp;
      pp *= ((lane >> (6 - d)) & 1) ? p : (1.f - p);
    }
    float p7 = wsp[63 + lane];
    s0r[6] += pp;
    s1r[6] += p7 * pp;
    float pL = pp * (1.f - p7), pR = pp * p7;
    float p8a = wsp[127 + 2 * lane], p8b = wsp[128 + 2 * lane];
    float lf0 = pL * (1.f - p8a), lf1 = pL * p8a;
    float lf2 = pR * (1.f - p8b), lf3 = pR * p8b;
    float4 lq = *(const float4*)(logQT + (size_t)tg * NPAD + lane * 4);
    wdot += lf0 * lq.x + lf1 * lq.y + lf2 * lq.z + lf3 * lq.w;
    float bv = lf0; int bi = 4 * lane;
    if (lf1 > bv) { bv = lf1; bi = 4 * lane + 1; }
    if (lf2 > bv) { bv = lf2; bi = 4 * lane + 2; }
    if (lf3 > bv) { bv = lf3; bi = 4 * lane + 3; }
    for (int off = 32; off; off >>= 1) {
      float ov = __shfl_down(bv, off);
      int oi = __shfl_down(bi, off);
      if (ov > bv || (ov == bv && oi < bi)) { bv = ov; bi = oi; }  // first-max tie-break
    }
    if (lane == 0) best[r] = bi;
  }
  // fold per-wave node sums into block LDS arrays
#pragma unroll
  for (int d = 1; d <= 6; ++d) {
    int idx = (1 << (d - 1)) - 1 + (lane >> (7 - d));
    if ((lane & ((1 << (7 - d)) - 1)) == 0) {
      atomicAdd(&s0s[idx], s0r[d - 1]);
      atomicAdd(&s1s[idx], s1r[d - 1]);
    }
  }
  atomicAdd(&s0s[63 + lane], s0r[6]);
  atomicAdd(&s1s[63 + lane], s1r[6]);
  for (int off = 32; off; off >>= 1) wdot += __shfl_down(wdot, off);
  if (lane == 0) atomicAdd(&sdot, wdot);
  __syncthreads();
  if (tid < 127) {
    atomicAdd(&acc[tid], s0s[tid]);
    atomicAdd(&acc[127 + tid], s1s[tid]);
  }
  if (tid == 255) atomicAdd(&acc[254], sdot);
}

__global__ __launch_bounds__(128) void finalize_loss(const float* __restrict__ acc,
                                                     float* __restrict__ out) {
  __shared__ float red[128];
  int t = threadIdx.x;
  float c = 0.f;
  if (t < 127) {
    float denom = acc[t];
    if (denom == 0.f) denom = 1e-6f;
    float alpha = acc[127 + t] / denom;
    alpha = fminf(fmaxf(alpha, 1e-6f), 1.f - 1e-6f);
    int d = 31 - __clz(t + 1) + 1;  // depth: idx 0 -> 1, idx 1..2 -> 2, ...
    float lm = 0.1f * exp2f(-(float)d);
    c = -lm * 0.5f * (logf(alpha) + log1pf(-alpha));
  }
  red[t] = c;
  __syncthreads();
  for (int s = 64; s; s >>= 1) { if (t < s) red[t] += red[t + s]; __syncthreads(); }
  if (t == 0) out[0] = -(acc[254] / 16384.f) + red[0];
}

__global__ __launch_bounds__(256) void gather_rows(const float* __restrict__ Q,
                                                   const int* __restrict__ best,
                                                   float* __restrict__ out) {
  int wv = threadIdx.x >> 6, lane = threadIdx.x & 63;
  int r = blockIdx.x * 4 + wv;
  const float* src = Q + (size_t)best[r] * NCLS;
  float* dst = out + 1 + (size_t)r * NCLS;  // rows start at global index 1+1000r
  if (lane < 3) dst[lane] = src[lane];
  if (lane == 0) dst[999] = src[999];
#pragma unroll
  for (int i = 0; i < 4; ++i) {
    int q = i * 64 + lane;
    if (q < 249) {
      int o = 3 + 4 * q;  // 16B-aligned in dst
      float4 v = make_float4(src[o], src[o + 1], src[o + 2], src[o + 3]);
      *(float4*)(dst + o) = v;
    }
  }
}

extern "C" void kernel_launch(void* const* d_in, const int* in_sizes, int n_in,
                              void* d_out, int out_size, void* d_ws, size_t ws_size,
                              hipStream_t stream) {
  const float* x = (const float*)d_in[0];
  const float* y = (const float*)d_in[1];
  const float* W = (const float*)d_in[2];
  const float* b = (const float*)d_in[3];
  const float* beta = (const float*)d_in[4];
  const float* leaf = (const float*)d_in[5];
  float* out = (float*)d_out;
  char* ws = (char*)d_ws;

  unsigned short* WbP = (unsigned short*)(ws + 0);       // 1048576 (fragment-major)
  float* bp    = (float*)(ws + 1048576);                 // 1024
  float* betap = (float*)(ws + 1049600);                 // 1024
  float* accb  = (float*)(ws + 1050624);                 // 1024 (255 used)
  int* tgt     = (int*)(ws + 1051648);                   // 65536
  int* best    = (int*)(ws + 1117184);                   // 65536
  float* logQT = (float*)(ws + 1182720);                 // 1000*256*4 = 1024000
  float* Q     = (float*)(ws + 2206720);                 // 1024000

  prep_w<<<256, 256, 0, stream>>>(W, b, beta, WbP, bp, betap);
  leaf_softmax<<<256, 256, 0, stream>>>(leaf, logQT, Q);
  find_targets<<<4096, 256, 0, stream>>>(y, tgt);
  hipMemsetAsync(accb, 0, 256 * sizeof(float), stream);
  gemm_tree<<<512, 256, 0, stream>>>(x, WbP, bp, betap, logQT, tgt, accb, best);
  finalize_loss<<<1, 128, 0, stream>>>(accb, out);
  gather_rows<<<4096, 256, 0, stream>>>(Q, best, out);
}